// Round 6
// baseline (326.465 us; speedup 1.0000x reference)
//
#include <hip/hip_runtime.h>
#include <hip/hip_bf16.h>

namespace {
constexpr int B = 64, L = 1024, D = 64;
constexpr int PSTRIDE = 40;  // bf16; 80 B rows keep b128 reads 16B-aligned
constexpr int QSPLIT = 2;    // q-range halves; partial O via atomicAdd
constexpr int QRANGE = L / QSPLIT;

typedef float f32x4 __attribute__((ext_vector_type(4)));
typedef int   i32x4 __attribute__((ext_vector_type(4)));
typedef __bf16 bf16x8 __attribute__((ext_vector_type(8)));

__device__ inline bf16x8 cvt8(f32x4 a, f32x4 b) {
  bf16x8 r;
  r[0] = (__bf16)a[0]; r[1] = (__bf16)a[1]; r[2] = (__bf16)a[2]; r[3] = (__bf16)a[3];
  r[4] = (__bf16)b[0]; r[5] = (__bf16)b[1]; r[6] = (__bf16)b[2]; r[7] = (__bf16)b[3];
  return r;
}
}  // namespace

// Prep: VT[b][d][q] = bf16(V[b][q][d]);  QT[b][q][d] = bf16(Q[b][q][d] / 8).
__global__ __launch_bounds__(256)
void prep_kernel(const float* __restrict__ qp, const float* __restrict__ vp,
                 __bf16* __restrict__ qt, __bf16* __restrict__ vt) {
  __shared__ float t[64][65];
  const int tid = threadIdx.x;
  const int b = blockIdx.y;
  const int qb = blockIdx.x * 64;

  {  // V tile -> LDS (f32, padded)
    const int qr = tid >> 4, d0 = (tid & 15) * 4;
#pragma unroll
    for (int p = 0; p < 4; ++p) {
      f32x4 r = *reinterpret_cast<const f32x4*>(
          vp + ((size_t)(b * L + qb + p * 16 + qr)) * D + d0);
      *reinterpret_cast<f32x4*>(&t[p * 16 + qr][d0]) = r;
    }
  }
  {  // Q convert (scaled by 1/8)
    const int qr = tid >> 2, quad = tid & 3;
    const float* src = qp + ((size_t)(b * L + qb + qr)) * D + quad * 16;
    __bf16* dst = qt + (((size_t)(b * L + qb + qr)) << 6) + quad * 16;
#pragma unroll
    for (int h = 0; h < 2; ++h) {
      f32x4 a = *reinterpret_cast<const f32x4*>(src + h * 8);
      f32x4 bb = *reinterpret_cast<const f32x4*>(src + h * 8 + 4);
      a *= 0.125f; bb *= 0.125f;
      *reinterpret_cast<bf16x8*>(dst + h * 8) = cvt8(a, bb);
    }
  }
  __syncthreads();
  {  // transposed V out: VT rows = d, contiguous q
    const int qh = tid & 7, dr = tid >> 3;  // dr in 0..31
#pragma unroll
    for (int p = 0; p < 2; ++p) {
      const int d = p * 32 + dr;
      f32x4 x, y;
#pragma unroll
      for (int j = 0; j < 4; ++j) x[j] = t[qh * 8 + j][d];
#pragma unroll
      for (int j = 0; j < 4; ++j) y[j] = t[qh * 8 + 4 + j][d];
      *reinterpret_cast<bf16x8*>(vt + (((size_t)(b * D + d)) << 10) + qb + qh * 8) =
          cvt8(x, y);
    }
  }
}

// Main: block = 64 keys (4 waves x 16 k) x 512 q, one batch. 2048 blocks ->
// 8 blocks/CU; VGPR <= 64 (launch_bounds 256,8) -> 32 waves/CU for Little's
// law on the gate/mask/attn HBM streams. No barriers (P^T per-wave LDS,
// double-buffered). gate/mask prefetched one 32-q step ahead. Partial O
// accumulated via f32 atomicAdd onto zeroed output (2-way, commutative).
__global__ __launch_bounds__(256, 8)
void gated_attn_kernel(const __bf16* __restrict__ qt,
                       const float* __restrict__ kp,
                       const __bf16* __restrict__ vt,
                       const int* __restrict__ mask,
                       const float* __restrict__ gate,
                       float* __restrict__ out_o,
                       float* __restrict__ out_attn) {
  __shared__ __bf16 pt[4][2][16 * PSTRIDE];  // 10 KiB

  const int tid = threadIdx.x, wave = tid >> 6, lane = tid & 63;
  const int c = lane & 15, g = lane >> 4;
  const int b = blockIdx.y;
  const int kbase = blockIdx.x * 64 + wave * 16;
  const int q0base = blockIdx.z * QRANGE;

  // K fragments, loop-invariant (Q side carries the 1/8 scale)
  const float* krow = kp + ((size_t)(b * L + kbase + c)) * D + g * 8;
  const bf16x8 kf0 = cvt8(*reinterpret_cast<const f32x4*>(krow),
                          *reinterpret_cast<const f32x4*>(krow + 4));
  const bf16x8 kf1 = cvt8(*reinterpret_cast<const f32x4*>(krow + 32),
                          *reinterpret_cast<const f32x4*>(krow + 36));

  f32x4 acc[4] = {};  // O[k = kbase+g*4+i][d = t*16+c]

  // loop-invariant bases
  const __bf16* qtb = qt + (((size_t)(b * L + c)) << 6) + g * 8;
  const __bf16* vtb = vt + (((size_t)(b * D + c)) << 10) + g * 8;
  const size_t gmb = ((size_t)(b * L + c)) * L + kbase + g * 4;

  f32x4 gg[2]; i32x4 mm[2];

  auto load_gm = [&](int qq, f32x4* gd, i32x4* md) {
#pragma unroll
    for (int sub = 0; sub < 2; ++sub) {
      const size_t idx = gmb + (size_t)(qq + sub * 16) * L;
      gd[sub] = *reinterpret_cast<const f32x4*>(gate + idx);
      md[sub] = *reinterpret_cast<const i32x4*>(mask + idx);
    }
  };

  load_gm(q0base, gg, mm);

  for (int q0 = q0base; q0 < q0base + QRANGE; q0 += 32) {
    const int buf = (q0 >> 5) & 1;
    const int qpf = (q0 + 32 < q0base + QRANGE) ? q0 + 32 : q0base;

    // GEMM1: S^T[16k x 32q]; Q loaded at use (L2-hot, covered by occupancy)
    f32x4 s[2];
#pragma unroll
    for (int sub = 0; sub < 2; ++sub) {
      const __bf16* qrow = qtb + ((size_t)(q0 + sub * 16) << 6);
      f32x4 cc = {};
      cc = __builtin_amdgcn_mfma_f32_16x16x32_bf16(
          kf0, *reinterpret_cast<const bf16x8*>(qrow), cc, 0, 0, 0);
      cc = __builtin_amdgcn_mfma_f32_16x16x32_bf16(
          kf1, *reinterpret_cast<const bf16x8*>(qrow + 32), cc, 0, 0, 0);
      s[sub] = cc;
    }

    // sigmoid + attn store + P^T stage (per-wave LDS, no barrier)
    __bf16* myp = &pt[wave][buf][0];
#pragma unroll
    for (int sub = 0; sub < 2; ++sub) {
      const size_t idx = gmb + (size_t)(q0 + sub * 16) * L;
      f32x4 p;
#pragma unroll
      for (int i = 0; i < 4; ++i) {
        const float x = s[sub][i] * gg[sub][i];
        const float e = __expf(-x);
        p[i] = mm[sub][i] ? 0.0f : __builtin_amdgcn_rcpf(1.0f + e);
      }
      *reinterpret_cast<f32x4*>(out_attn + idx) = p;
#pragma unroll
      for (int i = 0; i < 4; ++i)
        myp[(g * 4 + i) * PSTRIDE + sub * 16 + c] = (__bf16)p[i];
    }

    load_gm(qpf, gg, mm);  // prefetch next step's HBM streams

    const bf16x8 pa =
        *reinterpret_cast<const bf16x8*>(&myp[c * PSTRIDE + g * 8]);

    // GEMM2: O += P^T V  (V^T loaded per-tile; L2-hot)
#pragma unroll
    for (int t = 0; t < 4; ++t) {
      const bf16x8 vf = *reinterpret_cast<const bf16x8*>(
          vtb + ((size_t)t << 14) + q0);  // (t*16)<<10 = t<<14
      acc[t] = __builtin_amdgcn_mfma_f32_16x16x32_bf16(pa, vf, acc[t], 0, 0, 0);
    }
  }

  // epilogue: partial-O accumulate (out_o zeroed by memset; 2-way atomics)
#pragma unroll
  for (int t = 0; t < 4; ++t)
#pragma unroll
    for (int i = 0; i < 4; ++i)
      atomicAdd(&out_o[((size_t)(b * L + kbase + g * 4 + i)) * D + t * 16 + c],
                acc[t][i]);
}

extern "C" void kernel_launch(void* const* d_in, const int* in_sizes, int n_in,
                              void* d_out, int out_size, void* d_ws, size_t ws_size,
                              hipStream_t stream) {
  const float* q = (const float*)d_in[0];
  const float* k = (const float*)d_in[1];
  const float* v = (const float*)d_in[2];
  const int* mask = (const int*)d_in[3];
  const float* gate = (const float*)d_in[4];

  float* out_o = (float*)d_out;                 // [B, L, D]
  float* out_attn = out_o + (size_t)B * L * D;  // [B, L, L]

  __bf16* qt = (__bf16*)d_ws;                   // [B, L, D] bf16 (scaled 1/8)
  __bf16* vt = qt + (size_t)B * L * D;          // [B, D, L] bf16

  hipMemsetAsync(out_o, 0, (size_t)B * L * D * sizeof(float), stream);
  prep_kernel<<<dim3(L / 64, B), dim3(256), 0, stream>>>(q, v, qt, vt);
  gated_attn_kernel<<<dim3(L / 64, B, QSPLIT), dim3(256), 0, stream>>>(
      qt, k, vt, mask, gate, out_o, out_attn);
}

// Round 7
// 200.893 us; speedup vs baseline: 1.6251x; 1.6251x over previous
//
#include <hip/hip_runtime.h>
#include <hip/hip_bf16.h>

namespace {
constexpr int B = 64, L = 1024, D = 64;
constexpr int KT = 256;        // k-window per block (1KB f32 rows -> contiguity)
constexpr int QS = 16;         // q per step
constexpr int NSTEP = L / QS;  // 64
constexpr int GP = 260;        // gate/attn LDS pitch (f32 words)
constexpr int MPB = 272;       // mask LDS pitch (bytes)
constexpr int PP = 40;         // P^T LDS pitch (bf16) -> 80B rows, b128-aligned

typedef float f32x4 __attribute__((ext_vector_type(4)));
typedef int   i32x4 __attribute__((ext_vector_type(4)));
typedef __bf16 bf16x8 __attribute__((ext_vector_type(8)));
typedef unsigned int u32;

__device__ inline bf16x8 cvt8(const float* __restrict__ p) {
  f32x4 a = *reinterpret_cast<const f32x4*>(p);
  f32x4 b = *reinterpret_cast<const f32x4*>(p + 4);
  bf16x8 r;
  r[0] = (__bf16)a[0]; r[1] = (__bf16)a[1]; r[2] = (__bf16)a[2]; r[3] = (__bf16)a[3];
  r[4] = (__bf16)b[0]; r[5] = (__bf16)b[1]; r[6] = (__bf16)b[2]; r[7] = (__bf16)b[3];
  return r;
}
}  // namespace

// Prep: VT[b][d][q] = bf16(V[b][q][d]);  QT[b][q][d] = bf16(Q[b][q][d] / 8).
__global__ __launch_bounds__(256)
void prep_kernel(const float* __restrict__ qp, const float* __restrict__ vp,
                 __bf16* __restrict__ qt, __bf16* __restrict__ vt) {
  __shared__ float t[64][65];
  const int tid = threadIdx.x;
  const int b = blockIdx.y;
  const int qb = blockIdx.x * 64;

  {  // V tile -> LDS (f32, padded)
    const int qr = tid >> 4, d0 = (tid & 15) * 4;
#pragma unroll
    for (int p = 0; p < 4; ++p) {
      f32x4 r = *reinterpret_cast<const f32x4*>(
          vp + ((size_t)(b * L + qb + p * 16 + qr)) * D + d0);
      *reinterpret_cast<f32x4*>(&t[p * 16 + qr][d0]) = r;
    }
  }
  {  // Q convert (scaled by 1/8)
    const int qr = tid >> 2, quad = tid & 3;
    const float* src = qp + ((size_t)(b * L + qb + qr)) * D + quad * 16;
    __bf16* dst = qt + (((size_t)(b * L + qb + qr)) << 6) + quad * 16;
#pragma unroll
    for (int h = 0; h < 2; ++h) {
      f32x4 a = *reinterpret_cast<const f32x4*>(src + h * 8);
      f32x4 bb = *reinterpret_cast<const f32x4*>(src + h * 8 + 4);
      a *= 0.125f; bb *= 0.125f;
      bf16x8 r;
#pragma unroll
      for (int j = 0; j < 4; ++j) { r[j] = (__bf16)a[j]; r[4 + j] = (__bf16)bb[j]; }
      *reinterpret_cast<bf16x8*>(dst + h * 8) = r;
    }
  }
  __syncthreads();
  {  // transposed V out: VT rows = d, contiguous q
    const int qh = tid & 7, dr = tid >> 3;
#pragma unroll
    for (int p = 0; p < 2; ++p) {
      const int d = p * 32 + dr;
      bf16x8 r;
#pragma unroll
      for (int j = 0; j < 8; ++j) r[j] = (__bf16)t[qh * 8 + j][d];
      *reinterpret_cast<bf16x8*>(vt + (((size_t)(b * D + d)) << 10) + qb + qh * 8) = r;
    }
  }
}

// Main: block = (batch, 256-k window), 8 waves (512 thr), full q sweep.
// Per 16-q step: cooperative 1KB-contiguous gate/mask loads -> LDS;
// GEMM1 in frag layout; sigmoid from LDS-staged gate/mask; attn staged to
// LDS and written back cooperatively (1KB-contiguous); P^T wave-private in
// LDS; GEMM2 (K=32) every 2 steps. Two barriers/step, all single-buffered.
__global__ __launch_bounds__(512)
void gated_attn_kernel(const __bf16* __restrict__ qt,
                       const float* __restrict__ kp,
                       const __bf16* __restrict__ vt,
                       const int* __restrict__ mask,
                       const float* __restrict__ gate,
                       float* __restrict__ out_o,
                       float* __restrict__ out_attn) {
  __shared__ float gbuf[QS * GP];           // 16.6 KB gate tile
  __shared__ float abuf[QS * GP];           // 16.6 KB attn tile
  __shared__ unsigned char mbuf[QS * MPB];  //  4.3 KB mask bytes
  __shared__ __bf16 pbuf[KT * PP];          // 20.5 KB P^T (wave-private rows)

  const int tid = threadIdx.x, w = tid >> 6, lane = tid & 63;
  const int c = lane & 15, g = lane >> 4;

  // XCD-grouped decode: all 4 k-blocks of a batch share an XCD (L2 reuse).
  const int i = blockIdx.x;
  const int b = (i & 7) * 8 + (i >> 5);
  const int ktile = ((i >> 3) & 3) * KT;
  const int kw = ktile + w * 32;

  // cooperative staging coords: 32 threads/row, 2 chunks of 16B per thread
  const int srow = tid >> 5, scol = (tid & 31) * 4;

  // K fragments (A operand of GEMM1), loop-invariant
  bf16x8 kf[2][2];
#pragma unroll
  for (int ks = 0; ks < 2; ++ks)
#pragma unroll
    for (int h = 0; h < 2; ++h)
      kf[ks][h] = cvt8(kp + ((size_t)(b * L + kw + ks * 16 + c)) * D + h * 32 + g * 8);

  f32x4 acc[2][4] = {};  // O[k=kw+ks*16+g*4+j][d=ds*16+c]

  f32x4 sg0, sg1; i32x4 sm0, sm1;  // staged gate/mask regs (1-step pipeline)
  bf16x8 qf0, qf1;

  auto issue_gm = [&](int q0) {
    const float* gp_ = gate + ((size_t)(b * L + q0 + srow)) * L + ktile + scol;
    sg0 = *reinterpret_cast<const f32x4*>(gp_);
    sg1 = *reinterpret_cast<const f32x4*>(gp_ + 128);
    const int* mp_ = mask + ((size_t)(b * L + q0 + srow)) * L + ktile + scol;
    sm0 = *reinterpret_cast<const i32x4*>(mp_);
    sm1 = *reinterpret_cast<const i32x4*>(mp_ + 128);
  };
  auto write_gm = [&]() {
    *reinterpret_cast<f32x4*>(&gbuf[srow * GP + scol]) = sg0;
    *reinterpret_cast<f32x4*>(&gbuf[srow * GP + scol + 128]) = sg1;
    const u32 p0 = (u32)(sm0[0] & 1) | ((u32)(sm0[1] & 1) << 8) |
                   ((u32)(sm0[2] & 1) << 16) | ((u32)(sm0[3] & 1) << 24);
    const u32 p1 = (u32)(sm1[0] & 1) | ((u32)(sm1[1] & 1) << 8) |
                   ((u32)(sm1[2] & 1) << 16) | ((u32)(sm1[3] & 1) << 24);
    *reinterpret_cast<u32*>(&mbuf[srow * MPB + scol]) = p0;
    *reinterpret_cast<u32*>(&mbuf[srow * MPB + scol + 128]) = p1;
  };
  auto load_qf = [&](int q0) {
    const __bf16* qr = qt + (((size_t)(b * L + q0 + c)) << 6) + g * 8;
    qf0 = *reinterpret_cast<const bf16x8*>(qr);
    qf1 = *reinterpret_cast<const bf16x8*>(qr + 32);
  };

  // prologue: tile 0 into LDS, tile 1 into regs
  issue_gm(0);
  write_gm();
  issue_gm(QS);
  load_qf(0);
  __syncthreads();

  for (int t = 0; t < NSTEP; ++t) {
    const int par = t & 1, q0 = t * QS;

    // GEMM1: S^T[32k_w x 16q]
    f32x4 s[2];
#pragma unroll
    for (int ks = 0; ks < 2; ++ks) {
      f32x4 cc = {};
      cc = __builtin_amdgcn_mfma_f32_16x16x32_bf16(kf[ks][0], qf0, cc, 0, 0, 0);
      cc = __builtin_amdgcn_mfma_f32_16x16x32_bf16(kf[ks][1], qf1, cc, 0, 0, 0);
      s[ks] = cc;
    }
    if (t + 1 < NSTEP) load_qf(q0 + QS);  // prefetch next Q (L2-hot)

    // elementwise from LDS-staged gate/mask; stage attn + P^T
#pragma unroll
    for (int ks = 0; ks < 2; ++ks) {
      const int kl = w * 32 + ks * 16 + g * 4;
      const f32x4 gv = *reinterpret_cast<const f32x4*>(&gbuf[c * GP + kl]);
      const u32 mv = *reinterpret_cast<const u32*>(&mbuf[c * MPB + kl]);
      f32x4 p;
#pragma unroll
      for (int j = 0; j < 4; ++j) {
        const float x = s[ks][j] * gv[j];
        const float e = __expf(-x);
        p[j] = ((mv >> (8 * j)) & 0xffu) ? 0.0f : __builtin_amdgcn_rcpf(1.0f + e);
      }
      *reinterpret_cast<f32x4*>(&abuf[c * GP + kl]) = p;
#pragma unroll
      for (int j = 0; j < 4; ++j)
        pbuf[(kl + j) * PP + par * 16 + c] = (__bf16)p[j];
    }

    __syncthreads();  // attn/P visible; gbuf/mbuf reads done

    // GEMM2 every q-pair (K=32); pbuf rows are this wave's own writes
    if (par == 1) {
      const int qp0 = (t >> 1) * 32;
#pragma unroll
      for (int ks = 0; ks < 2; ++ks) {
        const bf16x8 pa = *reinterpret_cast<const bf16x8*>(
            &pbuf[(w * 32 + ks * 16 + c) * PP + g * 8]);
#pragma unroll
        for (int ds = 0; ds < 4; ++ds) {
          const bf16x8 vf = *reinterpret_cast<const bf16x8*>(
              vt + (((size_t)(b * D + ds * 16 + c)) << 10) + qp0 + g * 8);
          acc[ks][ds] =
              __builtin_amdgcn_mfma_f32_16x16x32_bf16(pa, vf, acc[ks][ds], 0, 0, 0);
        }
      }
    }

    // cooperative contiguous attn writeback (1KB runs)
    {
      const f32x4 a0 = *reinterpret_cast<const f32x4*>(&abuf[srow * GP + scol]);
      const f32x4 a1 = *reinterpret_cast<const f32x4*>(&abuf[srow * GP + scol + 128]);
      float* op = out_attn + ((size_t)(b * L + q0 + srow)) * L + ktile + scol;
      *reinterpret_cast<f32x4*>(op) = a0;
      *reinterpret_cast<f32x4*>(op + 128) = a1;
    }

    // commit staged regs (t+1) to LDS; issue loads for t+2
    write_gm();
    if (t + 2 < NSTEP) issue_gm(q0 + 2 * QS);

    __syncthreads();  // staged tile visible for step t+1
  }

  // epilogue: O direct stores
#pragma unroll
  for (int ks = 0; ks < 2; ++ks)
#pragma unroll
    for (int ds = 0; ds < 4; ++ds)
#pragma unroll
      for (int j = 0; j < 4; ++j)
        out_o[((size_t)(b * L + kw + ks * 16 + g * 4 + j)) * D + ds * 16 + c] =
            acc[ks][ds][j];
}

extern "C" void kernel_launch(void* const* d_in, const int* in_sizes, int n_in,
                              void* d_out, int out_size, void* d_ws, size_t ws_size,
                              hipStream_t stream) {
  const float* q = (const float*)d_in[0];
  const float* k = (const float*)d_in[1];
  const float* v = (const float*)d_in[2];
  const int* mask = (const int*)d_in[3];
  const float* gate = (const float*)d_in[4];

  float* out_o = (float*)d_out;                 // [B, L, D]
  float* out_attn = out_o + (size_t)B * L * D;  // [B, L, L]

  __bf16* qt = (__bf16*)d_ws;                   // [B, L, D] bf16 (scaled 1/8)
  __bf16* vt = qt + (size_t)B * L * D;          // [B, D, L] bf16

  prep_kernel<<<dim3(L / 64, B), dim3(256), 0, stream>>>(q, v, qt, vt);
  gated_attn_kernel<<<dim3(256), dim3(512), 0, stream>>>(
      qt, k, vt, mask, gate, out_o, out_attn);
}

// Round 8
// 200.386 us; speedup vs baseline: 1.6292x; 1.0025x over previous
//
#include <hip/hip_runtime.h>
#include <hip/hip_bf16.h>

namespace {
constexpr int B = 64, L = 1024, D = 64;
constexpr int KT = 256;        // k-window per block (1KB f32 rows -> contiguity)
constexpr int QS = 16;         // q per step
constexpr int NSTEP = L / QS;  // 64
constexpr int GP = 260;        // gate/attn LDS pitch (f32 words)
constexpr int MPB = 272;       // mask LDS pitch (bytes)
constexpr int PP = 40;         // P^T LDS pitch (bf16) -> 80B rows, b128-aligned

typedef float f32x4 __attribute__((ext_vector_type(4)));
typedef int   i32x4 __attribute__((ext_vector_type(4)));
typedef __bf16 bf16x8 __attribute__((ext_vector_type(8)));
typedef unsigned int u32;

__device__ inline bf16x8 cvt8(const float* __restrict__ p) {
  f32x4 a = *reinterpret_cast<const f32x4*>(p);
  f32x4 b = *reinterpret_cast<const f32x4*>(p + 4);
  bf16x8 r;
  r[0] = (__bf16)a[0]; r[1] = (__bf16)a[1]; r[2] = (__bf16)a[2]; r[3] = (__bf16)a[3];
  r[4] = (__bf16)b[0]; r[5] = (__bf16)b[1]; r[6] = (__bf16)b[2]; r[7] = (__bf16)b[3];
  return r;
}

// Barrier with LDS-only drain: cross-wave deps here are purely LDS, so skip
// the vmcnt(0) drain __syncthreads would emit (it would serialize the
// gate/mask prefetch -> full HBM latency exposed per step).
__device__ inline void bar_lds() {
  asm volatile("s_waitcnt lgkmcnt(0)" ::: "memory");
  __builtin_amdgcn_s_barrier();
}
}  // namespace

// Prep: VT[b][d][q] = bf16(V[b][q][d]);  QT[b][q][d] = bf16(Q[b][q][d] / 8).
__global__ __launch_bounds__(256)
void prep_kernel(const float* __restrict__ qp, const float* __restrict__ vp,
                 __bf16* __restrict__ qt, __bf16* __restrict__ vt) {
  __shared__ float t[64][65];
  const int tid = threadIdx.x;
  const int b = blockIdx.y;
  const int qb = blockIdx.x * 64;

  {  // V tile -> LDS (f32, padded)
    const int qr = tid >> 4, d0 = (tid & 15) * 4;
#pragma unroll
    for (int p = 0; p < 4; ++p) {
      f32x4 r = *reinterpret_cast<const f32x4*>(
          vp + ((size_t)(b * L + qb + p * 16 + qr)) * D + d0);
      *reinterpret_cast<f32x4*>(&t[p * 16 + qr][d0]) = r;
    }
  }
  {  // Q convert (scaled by 1/8)
    const int qr = tid >> 2, quad = tid & 3;
    const float* src = qp + ((size_t)(b * L + qb + qr)) * D + quad * 16;
    __bf16* dst = qt + (((size_t)(b * L + qb + qr)) << 6) + quad * 16;
#pragma unroll
    for (int h = 0; h < 2; ++h) {
      f32x4 a = *reinterpret_cast<const f32x4*>(src + h * 8);
      f32x4 bb = *reinterpret_cast<const f32x4*>(src + h * 8 + 4);
      a *= 0.125f; bb *= 0.125f;
      bf16x8 r;
#pragma unroll
      for (int j = 0; j < 4; ++j) { r[j] = (__bf16)a[j]; r[4 + j] = (__bf16)bb[j]; }
      *reinterpret_cast<bf16x8*>(dst + h * 8) = r;
    }
  }
  __syncthreads();
  {  // transposed V out: VT rows = d, contiguous q
    const int qh = tid & 7, dr = tid >> 3;
#pragma unroll
    for (int p = 0; p < 2; ++p) {
      const int d = p * 32 + dr;
      bf16x8 r;
#pragma unroll
      for (int j = 0; j < 8; ++j) r[j] = (__bf16)t[qh * 8 + j][d];
      *reinterpret_cast<bf16x8*>(vt + (((size_t)(b * D + d)) << 10) + qb + qh * 8) = r;
    }
  }
}

// Main: block = (batch, 256-k window), 8 waves (512 thr), full q sweep.
// Per 16-q step: cooperative 1KB-contiguous gate/mask loads -> LDS;
// GEMM1 in frag layout; sigmoid from LDS-staged gate/mask; attn staged to
// LDS and written back cooperatively (1KB-contiguous); P^T wave-private in
// LDS; GEMM2 (K=32) every 2 steps. Two LDS-only barriers/step (no vmcnt
// drain -> gate/mask prefetch stays in flight across barriers).
__global__ __launch_bounds__(512)
void gated_attn_kernel(const __bf16* __restrict__ qt,
                       const float* __restrict__ kp,
                       const __bf16* __restrict__ vt,
                       const int* __restrict__ mask,
                       const float* __restrict__ gate,
                       float* __restrict__ out_o,
                       float* __restrict__ out_attn) {
  __shared__ float gbuf[QS * GP];           // 16.6 KB gate tile
  __shared__ float abuf[QS * GP];           // 16.6 KB attn tile
  __shared__ unsigned char mbuf[QS * MPB];  //  4.3 KB mask bytes
  __shared__ __bf16 pbuf[KT * PP];          // 20.5 KB P^T (wave-private rows)

  const int tid = threadIdx.x, w = tid >> 6, lane = tid & 63;
  const int c = lane & 15, g = lane >> 4;

  // XCD-grouped decode: all 4 k-blocks of a batch share an XCD (L2 reuse).
  const int i = blockIdx.x;
  const int b = (i & 7) * 8 + (i >> 5);
  const int ktile = ((i >> 3) & 3) * KT;
  const int kw = ktile + w * 32;

  // cooperative staging coords: 32 threads/row, 2 chunks of 16B per thread
  const int srow = tid >> 5, scol = (tid & 31) * 4;

  // K fragments (A operand of GEMM1), loop-invariant
  bf16x8 kf[2][2];
#pragma unroll
  for (int ks = 0; ks < 2; ++ks)
#pragma unroll
    for (int h = 0; h < 2; ++h)
      kf[ks][h] = cvt8(kp + ((size_t)(b * L + kw + ks * 16 + c)) * D + h * 32 + g * 8);

  f32x4 acc[2][4] = {};  // O[k=kw+ks*16+g*4+j][d=ds*16+c]

  f32x4 sg0, sg1; i32x4 sm0, sm1;  // staged gate/mask regs (1-step pipeline)
  bf16x8 qf0, qf1;

  auto issue_gm = [&](int q0) {
    const float* gp_ = gate + ((size_t)(b * L + q0 + srow)) * L + ktile + scol;
    sg0 = *reinterpret_cast<const f32x4*>(gp_);
    sg1 = *reinterpret_cast<const f32x4*>(gp_ + 128);
    const int* mp_ = mask + ((size_t)(b * L + q0 + srow)) * L + ktile + scol;
    sm0 = *reinterpret_cast<const i32x4*>(mp_);
    sm1 = *reinterpret_cast<const i32x4*>(mp_ + 128);
  };
  auto write_gm = [&]() {
    *reinterpret_cast<f32x4*>(&gbuf[srow * GP + scol]) = sg0;
    *reinterpret_cast<f32x4*>(&gbuf[srow * GP + scol + 128]) = sg1;
    const u32 p0 = (u32)(sm0[0] & 1) | ((u32)(sm0[1] & 1) << 8) |
                   ((u32)(sm0[2] & 1) << 16) | ((u32)(sm0[3] & 1) << 24);
    const u32 p1 = (u32)(sm1[0] & 1) | ((u32)(sm1[1] & 1) << 8) |
                   ((u32)(sm1[2] & 1) << 16) | ((u32)(sm1[3] & 1) << 24);
    *reinterpret_cast<u32*>(&mbuf[srow * MPB + scol]) = p0;
    *reinterpret_cast<u32*>(&mbuf[srow * MPB + scol + 128]) = p1;
  };
  auto load_qf = [&](int q0) {
    const __bf16* qr = qt + (((size_t)(b * L + q0 + c)) << 6) + g * 8;
    qf0 = *reinterpret_cast<const bf16x8*>(qr);
    qf1 = *reinterpret_cast<const bf16x8*>(qr + 32);
  };

  // prologue: tile 0 into LDS, tile 1 into regs
  issue_gm(0);
  write_gm();
  issue_gm(QS);
  load_qf(0);
  __syncthreads();

  for (int t = 0; t < NSTEP; ++t) {
    const int par = t & 1, q0 = t * QS;

    // GEMM1: S^T[32k_w x 16q]
    f32x4 s[2];
#pragma unroll
    for (int ks = 0; ks < 2; ++ks) {
      f32x4 cc = {};
      cc = __builtin_amdgcn_mfma_f32_16x16x32_bf16(kf[ks][0], qf0, cc, 0, 0, 0);
      cc = __builtin_amdgcn_mfma_f32_16x16x32_bf16(kf[ks][1], qf1, cc, 0, 0, 0);
      s[ks] = cc;
    }
    if (t + 1 < NSTEP) load_qf(q0 + QS);  // prefetch next Q (L2-hot)

    // elementwise from LDS-staged gate/mask; stage attn + P^T
#pragma unroll
    for (int ks = 0; ks < 2; ++ks) {
      const int kl = w * 32 + ks * 16 + g * 4;
      const f32x4 gv = *reinterpret_cast<const f32x4*>(&gbuf[c * GP + kl]);
      const u32 mv = *reinterpret_cast<const u32*>(&mbuf[c * MPB + kl]);
      f32x4 p;
#pragma unroll
      for (int j = 0; j < 4; ++j) {
        const float x = s[ks][j] * gv[j];
        const float e = __expf(-x);
        p[j] = ((mv >> (8 * j)) & 0xffu) ? 0.0f : __builtin_amdgcn_rcpf(1.0f + e);
      }
      *reinterpret_cast<f32x4*>(&abuf[c * GP + kl]) = p;
#pragma unroll
      for (int j = 0; j < 4; ++j)
        pbuf[(kl + j) * PP + par * 16 + c] = (__bf16)p[j];
    }

    bar_lds();  // attn/P visible; gbuf/mbuf reads done (LDS-only deps)

    // GEMM2 every q-pair (K=32); pbuf rows are this wave's own writes
    if (par == 1) {
      const int qp0 = (t >> 1) * 32;
#pragma unroll
      for (int ks = 0; ks < 2; ++ks) {
        const bf16x8 pa = *reinterpret_cast<const bf16x8*>(
            &pbuf[(w * 32 + ks * 16 + c) * PP + g * 8]);
#pragma unroll
        for (int ds = 0; ds < 4; ++ds) {
          const bf16x8 vf = *reinterpret_cast<const bf16x8*>(
              vt + (((size_t)(b * D + ds * 16 + c)) << 10) + qp0 + g * 8);
          acc[ks][ds] =
              __builtin_amdgcn_mfma_f32_16x16x32_bf16(pa, vf, acc[ks][ds], 0, 0, 0);
        }
      }
    }

    // cooperative contiguous attn writeback (1KB runs)
    {
      const f32x4 a0 = *reinterpret_cast<const f32x4*>(&abuf[srow * GP + scol]);
      const f32x4 a1 = *reinterpret_cast<const f32x4*>(&abuf[srow * GP + scol + 128]);
      float* op = out_attn + ((size_t)(b * L + q0 + srow)) * L + ktile + scol;
      *reinterpret_cast<f32x4*>(op) = a0;
      *reinterpret_cast<f32x4*>(op + 128) = a1;
    }

    // commit staged regs (t+1) to LDS; issue loads for t+2
    write_gm();
    if (t + 2 < NSTEP) issue_gm(q0 + 2 * QS);

    bar_lds();  // staged tile visible for step t+1 (LDS-only deps)
  }

  // epilogue: O direct stores
#pragma unroll
  for (int ks = 0; ks < 2; ++ks)
#pragma unroll
    for (int ds = 0; ds < 4; ++ds)
#pragma unroll
      for (int j = 0; j < 4; ++j)
        out_o[((size_t)(b * L + kw + ks * 16 + g * 4 + j)) * D + ds * 16 + c] =
            acc[ks][ds][j];
}

extern "C" void kernel_launch(void* const* d_in, const int* in_sizes, int n_in,
                              void* d_out, int out_size, void* d_ws, size_t ws_size,
                              hipStream_t stream) {
  const float* q = (const float*)d_in[0];
  const float* k = (const float*)d_in[1];
  const float* v = (const float*)d_in[2];
  const int* mask = (const int*)d_in[3];
  const float* gate = (const float*)d_in[4];

  float* out_o = (float*)d_out;                 // [B, L, D]
  float* out_attn = out_o + (size_t)B * L * D;  // [B, L, L]

  __bf16* qt = (__bf16*)d_ws;                   // [B, L, D] bf16 (scaled 1/8)
  __bf16* vt = qt + (size_t)B * L * D;          // [B, D, L] bf16

  prep_kernel<<<dim3(L / 64, B), dim3(256), 0, stream>>>(q, v, qt, vt);
  gated_attn_kernel<<<dim3(256), dim3(512), 0, stream>>>(
      qt, k, vt, mask, gate, out_o, out_attn);
}